// Round 7
// baseline (544.828 us; speedup 1.0000x reference)
//
#include <hip/hip_runtime.h>
#include <hip/hip_bf16.h>

typedef short s16x8 __attribute__((ext_vector_type(8)));
typedef float f32x4 __attribute__((ext_vector_type(4)));

#define C2 1536

__device__ __forceinline__ float b2f(ushort u){ return __uint_as_float(((unsigned)u)<<16); }
__device__ __forceinline__ ushort f2b(float f){ unsigned u = __float_as_uint(f); return (ushort)((u + 0x7fffu + ((u>>16)&1u)) >> 16); }

// ---------------- 128x128 bf16 MFMA GEMM, A(MxK) row-major, BT(NxK) row-major ----------------
// Fragment-order LDS (chunk c at ushort offset c*8): staging writes and fragment reads are
// lane-sequential -> 0 bank conflicts. K-loop: double-buffered LDS (ping-pong), ONE barrier
// per iteration, register prefetch distance 2 so the vmcnt wait before ds_write is long retired.
// EPI 0: o16[row*N+col]         = bf16(acc + bias[col])                        (V projection)
// EPI 1: g = gelu(acc+bias); col<1536 -> xr=o16, else xg=o16b                  (MLP GEMM1)
// EPI 2: o16[row*1536+768+col]  = bf16(xres[row*768+col] + scale[col]*(acc+bias))  (MLP GEMM2 -> xf right)
// EPI 3: o32[row*768+col]       = acc + bias[col] + xres[row*768+col]          (final)
template<int EPI>
__global__ __launch_bounds__(256) void gemm_bf16(
    const ushort* __restrict__ A, const ushort* __restrict__ BT,
    int M, int N, int K,
    const float* __restrict__ bias, const float* __restrict__ scale,
    const float* __restrict__ xres,
    ushort* __restrict__ o16, ushort* __restrict__ o16b, float* __restrict__ o32)
{
    __shared__ ushort Al[2][128*32];
    __shared__ ushort Bl[2][128*32];
    const int t = threadIdx.x;
    const int m0 = blockIdx.y*128, n0 = blockIdx.x*128;
    const int lane = t & 63, wv = t >> 6;
    const int wm = (wv>>1)*64, wn = (wv&1)*64;
    const int r0 = lane & 15, q = lane >> 4;

    // loader: chunk c -> global row ((c>>6)*16 + (c&15)), k-chunk ((c>>4)&3); LDS offset c*8 ushorts
    const int c0i = t, c1i = t + 256;
    const int lrow0 = ((c0i>>6)<<4) | (c0i&15), lkc0 = ((c0i>>4)&3) << 3;
    const int lrow1 = ((c1i>>6)<<4) | (c1i&15), lkc1 = ((c1i>>4)&3) << 3;
    const ushort* gA0 = A  + (size_t)(m0+lrow0)*K + lkc0;
    const ushort* gB0 = BT + (size_t)(n0+lrow0)*K + lkc0;
    const ushort* gA1 = A  + (size_t)(m0+lrow1)*K + lkc1;
    const ushort* gB1 = BT + (size_t)(n0+lrow1)*K + lkc1;

    f32x4 acc[4][4];
    #pragma unroll
    for (int i=0;i<4;++i)
        #pragma unroll
        for (int j=0;j<4;++j) acc[i][j] = (f32x4){0.f,0.f,0.f,0.f};

    const int nkt = K >> 5;
    // register tile-sets: slot s holds a staged 32-k tile awaiting its ds_write
    uint4 ra0[2], rb0[2], ra1[2], rb1[2];
    ra0[0] = *(const uint4*)gA0;        rb0[0] = *(const uint4*)gB0;
    ra1[0] = *(const uint4*)gA1;        rb1[0] = *(const uint4*)gB1;
    ra0[1] = *(const uint4*)(gA0 + 32); rb0[1] = *(const uint4*)(gB0 + 32);
    ra1[1] = *(const uint4*)(gA1 + 32); rb1[1] = *(const uint4*)(gB1 + 32);
    // stage tile 0 into buffer 0
    *(uint4*)&Al[0][c0i*8] = ra0[0];
    *(uint4*)&Bl[0][c0i*8] = rb0[0];
    *(uint4*)&Al[0][c1i*8] = ra1[0];
    *(uint4*)&Bl[0][c1i*8] = rb1[0];

    for (int kt = 0; kt < nkt; ++kt) {
        __syncthreads();
        const int cur = kt & 1, nxt = cur ^ 1;
        s16x8 af[4], bfr[4];
        #pragma unroll
        for (int mt=0; mt<4; ++mt) af[mt]  = *(const s16x8*)&Al[cur][(((wm>>4)+mt)*64 + lane)*8];
        #pragma unroll
        for (int nt=0; nt<4; ++nt) bfr[nt] = *(const s16x8*)&Bl[cur][(((wn>>4)+nt)*64 + lane)*8];
        if (kt+1 < nkt) {   // tile kt+1 (slot nxt) -> buffer nxt
            *(uint4*)&Al[nxt][c0i*8] = ra0[nxt];
            *(uint4*)&Bl[nxt][c0i*8] = rb0[nxt];
            *(uint4*)&Al[nxt][c1i*8] = ra1[nxt];
            *(uint4*)&Bl[nxt][c1i*8] = rb1[nxt];
        }
        if (kt+2 < nkt) {   // reload slot cur with tile kt+2
            ra0[cur] = *(const uint4*)(gA0 + (kt+2)*32);
            rb0[cur] = *(const uint4*)(gB0 + (kt+2)*32);
            ra1[cur] = *(const uint4*)(gA1 + (kt+2)*32);
            rb1[cur] = *(const uint4*)(gB1 + (kt+2)*32);
        }
        #pragma unroll
        for (int mt=0; mt<4; ++mt)
            #pragma unroll
            for (int nt=0; nt<4; ++nt)
                acc[mt][nt] = __builtin_amdgcn_mfma_f32_16x16x32_bf16(af[mt], bfr[nt], acc[mt][nt], 0,0,0);
    }

    #pragma unroll
    for (int mt=0; mt<4; ++mt) {
        #pragma unroll
        for (int nt=0; nt<4; ++nt) {
            int col = n0 + wn + nt*16 + r0;
            #pragma unroll
            for (int r=0; r<4; ++r) {
                int row = m0 + wm + mt*16 + q*4 + r;
                float v = acc[mt][nt][r];
                if (EPI == 0) {
                    o16[(size_t)row*N + col] = f2b(v + bias[col]);
                } else if (EPI == 1) {
                    v += bias[col];
                    float g = 0.5f*v*(1.0f + erff(v*0.70710678118f));
                    if (col < C2) o16 [(size_t)row*C2 + col]        = f2b(g);
                    else          o16b[(size_t)row*C2 + (col - C2)] = f2b(g);
                } else if (EPI == 2) {
                    v += bias[col];
                    o16[(size_t)row*1536 + 768 + col] = f2b(xres[(size_t)row*768 + col] + scale[col]*v);
                } else {
                    o32[(size_t)row*768 + col] = v + bias[col] + xres[(size_t)row*768 + col];
                }
            }
        }
    }
}

// ---------------- weight transpose + bf16 pack: dst[n*K+k] = bf16(src[k*ld + coff + n]) ----------------
__global__ __launch_bounds__(256) void pack_bt(const float* __restrict__ src, ushort* __restrict__ dst,
                                               int K, int ld, int coff)
{
    __shared__ float tl[32*33];
    int kt = blockIdx.x*32, nt = blockIdx.y*32;
    int nl = threadIdx.x & 31, kg = threadIdx.x >> 5;
    #pragma unroll
    for (int kk=0; kk<4; ++kk) {
        int k = kg*4 + kk;
        tl[k*33 + nl] = src[(size_t)(kt + k)*ld + coff + nt + nl];
    }
    __syncthreads();
    int kcol = threadIdx.x & 31, ng = threadIdx.x >> 5;
    #pragma unroll
    for (int nn=0; nn<4; ++nn) {
        int nrow = ng*4 + nn;
        dst[(size_t)(nt + nrow)*K + kt + kcol] = f2b(tl[kcol*33 + nrow]);
    }
}

__global__ __launch_bounds__(256) void pack_bv(const float* __restrict__ bqkv, float* __restrict__ bvp)
{
    int idx = blockIdx.x*256 + threadIdx.x;
    if (idx < 1536) bvp[idx] = bqkv[(idx/768)*2304 + 1536 + (idx%768)];
}

// ---------------- shared LN of x -> xa(ln1) and xm(ln2), bf16 ----------------
__global__ __launch_bounds__(256) void ln_x_kernel(const float* __restrict__ x,
    const float* __restrict__ g1, const float* __restrict__ b1,
    const float* __restrict__ g2, const float* __restrict__ b2,
    ushort* __restrict__ xa, ushort* __restrict__ xm)
{
    __shared__ float sb[8];
    int row = blockIdx.x; int t = threadIdx.x;
    float v[3]; float s = 0.f, ss = 0.f;
    #pragma unroll
    for (int e=0; e<3; ++e) { v[e] = x[(size_t)row*768 + t + e*256]; s += v[e]; ss += v[e]*v[e]; }
    for (int o=32; o>0; o>>=1){ s += __shfl_down(s,o,64); ss += __shfl_down(ss,o,64); }
    int lane = t&63, w = t>>6;
    if (lane==0){ sb[w]=s; sb[4+w]=ss; }
    __syncthreads();
    s = sb[0]+sb[1]+sb[2]+sb[3]; ss = sb[4]+sb[5]+sb[6]+sb[7];
    float mean = s*(1.f/768.f);
    float var  = ss*(1.f/768.f) - mean*mean;
    float rstd = rsqrtf(var + 1e-5f);
    #pragma unroll
    for (int e=0; e<3; ++e){
        int c = t + e*256;
        float n = (v[e]-mean)*rstd;
        xa[(size_t)row*768 + c] = f2b(n*g1[c] + b1[c]);
        xm[(size_t)row*768 + c] = f2b(n*g2[c] + b2[c]);
    }
}

// ---------------- prep: rope weight tables, reattn-LN wvec, init attn_c(bias) and vsum(0) ----------------
__global__ __launch_bounds__(256) void prep_kernel(
    float* __restrict__ w1t, float* __restrict__ w2t, float* __restrict__ wvec,
    float* __restrict__ attn_c, float* __restrict__ vsum,
    const float* __restrict__ R, const float* __restrict__ rng,
    const float* __restrict__ rnb, const float* __restrict__ bproj)
{
    int idx = blockIdx.x*256 + threadIdx.x;
    {   // rope tables for v-rope (scale = 1/sc)
        int i = idx >> 6, j = idx & 63;
        float w1, w2;
        if (j < 32) {
            int m = j >> 1;
            float inv = powf(10000.f, -(float)m*(1.f/16.f));
            float fr = (float)i * inv;
            float c = cosf(fr), sn = sinf(fr);
            float power = ((float)i - 512.f) * (1.f/512.f);
            float basev = (2.f*(float)(j & 15) + 12.8f) * (1.f/44.8f);
            float sfac = powf(basev, -power);          // 1/sc
            w1 = c * sfac;
            w2 = ((j & 1) ? sn : -sn) * sfac;
        } else { w1 = 1.f; w2 = 0.f; }
        w1t[idx] = w1; w2t[idx] = w2;
    }
    if (blockIdx.x >= 1 && blockIdx.x <= 12) {
        int k = (blockIdx.x-1)*256 + threadIdx.x;  // 0..3071
        int o = k % 768;
        attn_c[k] = bproj[o] + bproj[768 + o];
    }
    if (blockIdx.x >= 13 && blockIdx.x <= 36) {
        int k = (blockIdx.x-13)*256 + threadIdx.x; // 0..6143
        vsum[k] = 0.f;
    }
    if (blockIdx.x == 0) {
        __shared__ float mixs[24];
        __shared__ float ws[24];
        int t = threadIdx.x;
        if (t < 24) {
            int p = t / 12, g = t % 12;
            float m = 0.f;
            for (int h=0; h<12; ++h) m += R[p*144 + h*12 + g];
            mixs[t] = m;
        }
        __syncthreads();
        if (t < 2) {
            float mean=0.f, var=0.f;
            for (int g=0; g<12; ++g) mean += mixs[t*12+g];
            mean *= (1.f/12.f);
            for (int g=0; g<12; ++g){ float d = mixs[t*12+g]-mean; var += d*d; }
            var *= (1.f/12.f);
            float rstd = rsqrtf(var + 1e-5f);
            for (int g=0; g<12; ++g)
                ws[t*12+g] = (mixs[t*12+g]-mean)*rstd*rng[t*12+g] + rnb[t*12+g];
        }
        __syncthreads();
        if (t < 24) wvec[t] = ws[t];
    }
}

// ---------------- vsum[b][pc] += sum_i w1*V + w2*V_neighbor ----------------
__global__ __launch_bounds__(256) void rope_reduce(const ushort* __restrict__ V,
    const float* __restrict__ w1t, const float* __restrict__ w2t, float* __restrict__ vsum)
{
    int col = blockIdx.x*256 + threadIdx.x;
    int b = blockIdx.y;
    int i0 = blockIdx.z * 256;
    int j = col & 63;
    float acc = 0.f;
    const ushort* vp = V + (size_t)(b*1024 + i0)*1536;
    #pragma unroll 4
    for (int i=0; i<256; ++i) {
        float v1 = b2f(vp[(size_t)i*1536 + col]);
        float v2 = b2f(vp[(size_t)i*1536 + (col^1)]);
        int ii = i0 + i;
        acc += w1t[ii*64 + j]*v1 + w2t[ii*64 + j]*v2;
    }
    atomicAdd(&vsum[b*1536 + col], acc);
}

// ---------------- attn_c[b][o] += sum_c (wvec*vsum)[b][c] * Wproj[p][c][o] ----------------
__global__ __launch_bounds__(256) void attn_gemm(const float* __restrict__ vsum,
    const float* __restrict__ wvec, const float* __restrict__ Wproj, float* __restrict__ attn_c)
{
    int o  = blockIdx.x*256 + threadIdx.x;
    int c0 = blockIdx.y * 96;
    int b  = blockIdx.z;
    int p  = c0 / 768;
    float acc = 0.f;
    #pragma unroll 4
    for (int cc=0; cc<96; ++cc) {
        int c = c0 + cc;
        int cl = c - p*768;
        float y = wvec[p*12 + (cl>>6)] * vsum[b*1536 + c];
        acc += y * Wproj[(size_t)p*589824 + (size_t)cl*768 + o];
    }
    atomicAdd(&attn_c[b*768 + o], acc);
}

// ---------------- xf left half: bf16(x + ls1 * attn_c[b]) ----------------
__global__ __launch_bounds__(256) void xf_left(const float* __restrict__ x, const float* __restrict__ ls1,
    const float* __restrict__ attn_c, ushort* __restrict__ xf)
{
    int col = blockIdx.x*256 + threadIdx.x;
    int row = blockIdx.y;
    xf[(size_t)row*1536 + col] = f2b(x[(size_t)row*768 + col] + ls1[col]*attn_c[(row>>10)*768 + col]);
}

// ---------------- gate LN over 1536 ----------------
__global__ __launch_bounds__(256) void ln_gate(const ushort* __restrict__ xg,
    const float* __restrict__ g, const float* __restrict__ bta, ushort* __restrict__ out)
{
    __shared__ float sb[8];
    int row = blockIdx.x, t = threadIdx.x;
    float v[6]; float s=0.f, ss=0.f;
    #pragma unroll
    for (int e=0;e<6;++e){ v[e] = b2f(xg[(size_t)row*1536 + t + e*256]); s+=v[e]; ss+=v[e]*v[e]; }
    for (int o=32; o>0; o>>=1){ s += __shfl_down(s,o,64); ss += __shfl_down(ss,o,64); }
    int lane = t&63, w = t>>6;
    if (lane==0){ sb[w]=s; sb[4+w]=ss; }
    __syncthreads();
    s = sb[0]+sb[1]+sb[2]+sb[3]; ss = sb[4]+sb[5]+sb[6]+sb[7];
    float mean = s*(1.f/1536.f);
    float var  = ss*(1.f/1536.f) - mean*mean;
    float rstd = rsqrtf(var + 1e-5f);
    #pragma unroll
    for (int e=0;e<6;++e){
        int c = t + e*256;
        out[(size_t)row*1536 + c] = f2b((v[e]-mean)*rstd*g[c] + bta[c]);
    }
}

// ---------------- depthwise conv (K=21, same-pad) + xr multiply, LDS sliding window ----------------
// block: 64 channels x 128 output rows; thread: 1 channel x 32 rows
#define CROWS 128
#define CIN   (CROWS + 20)   // 148 staged input rows
#define CSTR  72             // padded LDS row stride (ushorts)
__global__ __launch_bounds__(256) void conv_mul(const ushort* __restrict__ xgln,
    const float* __restrict__ cw, const float* __restrict__ cb,
    const ushort* __restrict__ xr, ushort* __restrict__ u)
{
    __shared__ ushort tile[CIN * CSTR];   // 21312 B
    const int c0 = blockIdx.x * 64;
    const int i0 = blockIdx.y * CROWS;
    const int b  = blockIdx.z;
    const int t  = threadIdx.x;
    const size_t base = (size_t)b*1024*1536;

    // stage rows i0-10 .. i0+137 (zero outside [0,1024))
    #pragma unroll
    for (int it = 0; it < 5; ++it) {
        int idx = it*256 + t;            // uint4 slots: CIN*8 = 1184
        if (idx < CIN*8) {
            int r  = idx >> 3;
            int cq = (idx & 7) * 8;
            int si = i0 + r - 10;
            uint4 val = make_uint4(0u,0u,0u,0u);
            if (si >= 0 && si < 1024)
                val = *(const uint4*)(xgln + base + (size_t)si*1536 + c0 + cq);
            *(uint4*)&tile[r*CSTR + cq] = val;
        }
    }
    __syncthreads();

    const int ch = t & 63;
    const int o0 = (t >> 6) * 32;        // 4 waves x 32 rows = 128
    const int c  = c0 + ch;

    float w[21];
    #pragma unroll
    for (int k=0; k<21; ++k) w[k] = cw[c*21 + k];
    const float bias = cb[c];

    float win[21];
    #pragma unroll
    for (int j=0; j<20; ++j) win[j] = b2f(tile[(o0+j)*CSTR + ch]);

    #pragma unroll
    for (int j=0; j<32; ++j) {
        win[(j+20)%21] = b2f(tile[(o0+j+20)*CSTR + ch]);
        float acc = bias;
        #pragma unroll
        for (int k=0; k<21; ++k) acc += win[(j+k)%21] * w[k];
        size_t off = base + (size_t)(i0+o0+j)*1536 + c;
        u[off] = f2b(b2f(xr[off]) * acc);
    }
}

extern "C" void kernel_launch(void* const* d_in, const int* in_sizes, int n_in,
                              void* d_out, int out_size, void* d_ws, size_t ws_size,
                              hipStream_t stream)
{
    const float* x     = (const float*)d_in[0];
    const float* Wqkv  = (const float*)d_in[1];
    const float* bqkv  = (const float*)d_in[2];
    const float* Wproj = (const float*)d_in[3];
    const float* bproj = (const float*)d_in[4];
    const float* Rw    = (const float*)d_in[9];
    const float* rng   = (const float*)d_in[10];
    const float* rnb   = (const float*)d_in[11];
    const float* ln1g  = (const float*)d_in[12];
    const float* ln1b  = (const float*)d_in[13];
    const float* ln2g  = (const float*)d_in[14];
    const float* ln2b  = (const float*)d_in[15];
    const float* ls1   = (const float*)d_in[16];
    const float* ls2   = (const float*)d_in[17];
    const float* W1    = (const float*)d_in[18];
    const float* b1    = (const float*)d_in[19];
    const float* gng   = (const float*)d_in[20];
    const float* gnb   = (const float*)d_in[21];
    const float* cw    = (const float*)d_in[22];
    const float* cb    = (const float*)d_in[23];
    const float* W2    = (const float*)d_in[24];
    const float* b2    = (const float*)d_in[25];
    const float* Wout  = (const float*)d_in[26];
    const float* bout  = (const float*)d_in[27];
    float* out = (float*)d_out;

    char* ws = (char*)d_ws;
    size_t off = 0;
    auto alloc = [&](size_t bytes)->char* {
        char* p = ws + off;
        off += (bytes + 255) & ~(size_t)255;
        return p;
    };
    ushort* WvT   = (ushort*)alloc(1536*768*2);   // [pc][k]
    ushort* W1T   = (ushort*)alloc(3072*768*2);
    ushort* W2T   = (ushort*)alloc(768*1536*2);
    ushort* WoutT = (ushort*)alloc(768*1536*2);
    float*  bvp   = (float*)alloc(1536*4);
    float*  w1t   = (float*)alloc(65536*4);
    float*  w2t   = (float*)alloc(65536*4);
    float*  wvec  = (float*)alloc(24*4);
    float*  attnc = (float*)alloc(3072*4);
    float*  vsum  = (float*)alloc(6144*4);
    ushort* xa16  = (ushort*)alloc(4096*768*2);
    ushort* xm16  = (ushort*)alloc(4096*768*2);   // xa16+xm16 contiguous -> xgln alias
    ushort* V16   = (ushort*)alloc(4096*1536*2);  // aliased by xr16 after rope_reduce
    ushort* xg16  = (ushort*)alloc(4096*1536*2);  // aliased by u16 after ln_gate
    ushort* xf16  = (ushort*)alloc(4096*1536*2);
    ushort* xgln  = xa16;   // reuses xa16+xm16 region (dead by then)
    ushort* xr16  = V16;
    ushort* u16   = xg16;
    (void)ws_size; (void)n_in; (void)in_sizes; (void)out_size;

    // ---- weight packs ----
    for (int p = 0; p < 2; ++p)
        pack_bt<<<dim3(24, 24), 256, 0, stream>>>(Wqkv + (size_t)p*768*2304, WvT + (size_t)p*768*768,
                                                  768, 2304, 1536);
    pack_bt<<<dim3(24, 96), 256, 0, stream>>>(W1,   W1T,   768,  3072, 0);
    pack_bt<<<dim3(48, 24), 256, 0, stream>>>(W2,   W2T,   1536, 768,  0);
    pack_bt<<<dim3(48, 24), 256, 0, stream>>>(Wout, WoutT, 1536, 768,  0);
    pack_bv<<<dim3(6), 256, 0, stream>>>(bqkv, bvp);
    prep_kernel<<<dim3(256), 256, 0, stream>>>(w1t, w2t, wvec, attnc, vsum, Rw, rng, rnb, bproj);

    // ---- shared LN ----
    ln_x_kernel<<<dim3(4096), 256, 0, stream>>>(x, ln1g, ln1b, ln2g, ln2b, xa16, xm16);

    // ---- V projection (both paths) ----
    gemm_bf16<0><<<dim3(12, 32), 256, 0, stream>>>(xa16, WvT, 4096, 1536, 768,
                                                   bvp, nullptr, nullptr, V16, nullptr, nullptr);
    // ---- rope-weighted sequence sum ----
    rope_reduce<<<dim3(6, 4, 4), 256, 0, stream>>>(V16, w1t, w2t, vsum);
    // ---- reattn projection to per-batch constant ----
    attn_gemm<<<dim3(3, 16, 4), 256, 0, stream>>>(vsum, wvec, Wproj, attnc);
    // ---- xf left half ----
    xf_left<<<dim3(3, 4096), 256, 0, stream>>>(x, ls1, attnc, xf16);

    // ---- MLP ----
    gemm_bf16<1><<<dim3(24, 32), 256, 0, stream>>>(xm16, W1T, 4096, 3072, 768,
                                                   b1, nullptr, nullptr, xr16, xg16, nullptr);
    ln_gate<<<dim3(4096), 256, 0, stream>>>(xg16, gng, gnb, xgln);
    conv_mul<<<dim3(24, 8, 4), 256, 0, stream>>>(xgln, cw, cb, xr16, u16);
    gemm_bf16<2><<<dim3(6, 32), 256, 0, stream>>>(u16, W2T, 4096, 768, 1536,
                                                  b2, ls2, x, xf16, nullptr, nullptr);
    // ---- final projection + residual ----
    gemm_bf16<3><<<dim3(6, 32), 256, 0, stream>>>(xf16, WoutT, 4096, 768, 1536,
                                                  bout, nullptr, x, nullptr, nullptr, out);
}

// Round 8
// 369.298 us; speedup vs baseline: 1.4753x; 1.4753x over previous
//
#include <hip/hip_runtime.h>
#include <hip/hip_bf16.h>

typedef short s16x8 __attribute__((ext_vector_type(8)));
typedef float f32x4 __attribute__((ext_vector_type(4)));

#define C2 1536

__device__ __forceinline__ float b2f(ushort u){ return __uint_as_float(((unsigned)u)<<16); }
__device__ __forceinline__ ushort f2b(float f){ unsigned u = __float_as_uint(f); return (ushort)((u + 0x7fffu + ((u>>16)&1u)) >> 16); }

// ---------------- 128x128 bf16 MFMA GEMM, A(MxK) row-major, BT(NxK) row-major ----------------
// Fragment-order LDS (chunk c at ushort offset c*8): staging writes and fragment reads are
// lane-sequential -> 0 bank conflicts. K-loop: double-buffered LDS ping-pong, ONE barrier per
// tile, register prefetch distance 2. Loop unrolled x2 so ALL buffer/slot indices are
// compile-time (dynamic-indexed register arrays demote to scratch -> 299MB WRITE_SIZE in r7).
// Requires nkt even (K % 64 == 0; K=768/1536 here).
// EPI 0: o16[row*N+col]         = bf16(acc + bias[col])                        (V projection)
// EPI 1: g = gelu(acc+bias); col<1536 -> xr=o16, else xg=o16b                  (MLP GEMM1)
// EPI 2: o16[row*1536+768+col]  = bf16(xres[row*768+col] + scale[col]*(acc+bias))  (MLP GEMM2 -> xf right)
// EPI 3: o32[row*768+col]       = acc + bias[col] + xres[row*768+col]          (final)
template<int EPI>
__global__ __launch_bounds__(256) void gemm_bf16(
    const ushort* __restrict__ A, const ushort* __restrict__ BT,
    int M, int N, int K,
    const float* __restrict__ bias, const float* __restrict__ scale,
    const float* __restrict__ xres,
    ushort* __restrict__ o16, ushort* __restrict__ o16b, float* __restrict__ o32)
{
    __shared__ ushort Al[2][128*32];
    __shared__ ushort Bl[2][128*32];
    const int t = threadIdx.x;
    const int m0 = blockIdx.y*128, n0 = blockIdx.x*128;
    const int lane = t & 63, wv = t >> 6;
    const int wm = (wv>>1)*64, wn = (wv&1)*64;
    const int r0 = lane & 15, q = lane >> 4;

    // loader: chunk c -> global row ((c>>6)*16 + (c&15)), k-chunk ((c>>4)&3); LDS offset c*8 ushorts
    const int c0i = t, c1i = t + 256;
    const int lrow0 = ((c0i>>6)<<4) | (c0i&15), lkc0 = ((c0i>>4)&3) << 3;
    const int lrow1 = ((c1i>>6)<<4) | (c1i&15), lkc1 = ((c1i>>4)&3) << 3;
    const ushort* gA0 = A  + (size_t)(m0+lrow0)*K + lkc0;
    const ushort* gB0 = BT + (size_t)(n0+lrow0)*K + lkc0;
    const ushort* gA1 = A  + (size_t)(m0+lrow1)*K + lkc1;
    const ushort* gB1 = BT + (size_t)(n0+lrow1)*K + lkc1;

    f32x4 acc[4][4];
    #pragma unroll
    for (int i=0;i<4;++i)
        #pragma unroll
        for (int j=0;j<4;++j) acc[i][j] = (f32x4){0.f,0.f,0.f,0.f};

    const int nkt = K >> 5;   // even
    // named prefetch slots (NO arrays -> no dynamic indexing -> no scratch)
    uint4 pa0_0, pb0_0, pa1_0, pb1_0;   // slot 0 (even tiles)
    uint4 pa0_1, pb0_1, pa1_1, pb1_1;   // slot 1 (odd tiles)
    pa0_0 = *(const uint4*)gA0;        pb0_0 = *(const uint4*)gB0;
    pa1_0 = *(const uint4*)gA1;        pb1_0 = *(const uint4*)gB1;
    pa0_1 = *(const uint4*)(gA0 + 32); pb0_1 = *(const uint4*)(gB0 + 32);
    pa1_1 = *(const uint4*)(gA1 + 32); pb1_1 = *(const uint4*)(gB1 + 32);
    // stage tile 0 into buffer 0
    *(uint4*)&Al[0][c0i*8] = pa0_0;
    *(uint4*)&Bl[0][c0i*8] = pb0_0;
    *(uint4*)&Al[0][c1i*8] = pa1_0;
    *(uint4*)&Bl[0][c1i*8] = pb1_0;

    for (int kt = 0; kt < nkt; kt += 2) {
        // ---- phase A: consume buf0 (tile kt); stage tile kt+1 -> buf1; load tile kt+2 -> slot0
        __syncthreads();
        {
            s16x8 af[4], bfr[4];
            #pragma unroll
            for (int mt=0; mt<4; ++mt) af[mt]  = *(const s16x8*)&Al[0][(((wm>>4)+mt)*64 + lane)*8];
            #pragma unroll
            for (int nt=0; nt<4; ++nt) bfr[nt] = *(const s16x8*)&Bl[0][(((wn>>4)+nt)*64 + lane)*8];
            *(uint4*)&Al[1][c0i*8] = pa0_1;
            *(uint4*)&Bl[1][c0i*8] = pb0_1;
            *(uint4*)&Al[1][c1i*8] = pa1_1;
            *(uint4*)&Bl[1][c1i*8] = pb1_1;
            if (kt+2 < nkt) {
                pa0_0 = *(const uint4*)(gA0 + (kt+2)*32);
                pb0_0 = *(const uint4*)(gB0 + (kt+2)*32);
                pa1_0 = *(const uint4*)(gA1 + (kt+2)*32);
                pb1_0 = *(const uint4*)(gB1 + (kt+2)*32);
            }
            #pragma unroll
            for (int mt=0; mt<4; ++mt)
                #pragma unroll
                for (int nt=0; nt<4; ++nt)
                    acc[mt][nt] = __builtin_amdgcn_mfma_f32_16x16x32_bf16(af[mt], bfr[nt], acc[mt][nt], 0,0,0);
        }
        // ---- phase B: consume buf1 (tile kt+1); stage tile kt+2 -> buf0; load tile kt+3 -> slot1
        __syncthreads();
        {
            s16x8 af[4], bfr[4];
            #pragma unroll
            for (int mt=0; mt<4; ++mt) af[mt]  = *(const s16x8*)&Al[1][(((wm>>4)+mt)*64 + lane)*8];
            #pragma unroll
            for (int nt=0; nt<4; ++nt) bfr[nt] = *(const s16x8*)&Bl[1][(((wn>>4)+nt)*64 + lane)*8];
            if (kt+2 < nkt) {
                *(uint4*)&Al[0][c0i*8] = pa0_0;
                *(uint4*)&Bl[0][c0i*8] = pb0_0;
                *(uint4*)&Al[0][c1i*8] = pa1_0;
                *(uint4*)&Bl[0][c1i*8] = pb1_0;
            }
            if (kt+3 < nkt) {
                pa0_1 = *(const uint4*)(gA0 + (kt+3)*32);
                pb0_1 = *(const uint4*)(gB0 + (kt+3)*32);
                pa1_1 = *(const uint4*)(gA1 + (kt+3)*32);
                pb1_1 = *(const uint4*)(gB1 + (kt+3)*32);
            }
            #pragma unroll
            for (int mt=0; mt<4; ++mt)
                #pragma unroll
                for (int nt=0; nt<4; ++nt)
                    acc[mt][nt] = __builtin_amdgcn_mfma_f32_16x16x32_bf16(af[mt], bfr[nt], acc[mt][nt], 0,0,0);
        }
    }

    #pragma unroll
    for (int mt=0; mt<4; ++mt) {
        #pragma unroll
        for (int nt=0; nt<4; ++nt) {
            int col = n0 + wn + nt*16 + r0;
            #pragma unroll
            for (int r=0; r<4; ++r) {
                int row = m0 + wm + mt*16 + q*4 + r;
                float v = acc[mt][nt][r];
                if (EPI == 0) {
                    o16[(size_t)row*N + col] = f2b(v + bias[col]);
                } else if (EPI == 1) {
                    v += bias[col];
                    float g = 0.5f*v*(1.0f + erff(v*0.70710678118f));
                    if (col < C2) o16 [(size_t)row*C2 + col]        = f2b(g);
                    else          o16b[(size_t)row*C2 + (col - C2)] = f2b(g);
                } else if (EPI == 2) {
                    v += bias[col];
                    o16[(size_t)row*1536 + 768 + col] = f2b(xres[(size_t)row*768 + col] + scale[col]*v);
                } else {
                    o32[(size_t)row*768 + col] = v + bias[col] + xres[(size_t)row*768 + col];
                }
            }
        }
    }
}

// ---------------- weight transpose + bf16 pack: dst[n*K+k] = bf16(src[k*ld + coff + n]) ----------------
__global__ __launch_bounds__(256) void pack_bt(const float* __restrict__ src, ushort* __restrict__ dst,
                                               int K, int ld, int coff)
{
    __shared__ float tl[32*33];
    int kt = blockIdx.x*32, nt = blockIdx.y*32;
    int nl = threadIdx.x & 31, kg = threadIdx.x >> 5;
    #pragma unroll
    for (int kk=0; kk<4; ++kk) {
        int k = kg*4 + kk;
        tl[k*33 + nl] = src[(size_t)(kt + k)*ld + coff + nt + nl];
    }
    __syncthreads();
    int kcol = threadIdx.x & 31, ng = threadIdx.x >> 5;
    #pragma unroll
    for (int nn=0; nn<4; ++nn) {
        int nrow = ng*4 + nn;
        dst[(size_t)(nt + nrow)*K + kt + kcol] = f2b(tl[kcol*33 + nrow]);
    }
}

__global__ __launch_bounds__(256) void pack_bv(const float* __restrict__ bqkv, float* __restrict__ bvp)
{
    int idx = blockIdx.x*256 + threadIdx.x;
    if (idx < 1536) bvp[idx] = bqkv[(idx/768)*2304 + 1536 + (idx%768)];
}

// ---------------- shared LN of x -> xa(ln1) and xm(ln2), bf16 ----------------
__global__ __launch_bounds__(256) void ln_x_kernel(const float* __restrict__ x,
    const float* __restrict__ g1, const float* __restrict__ b1,
    const float* __restrict__ g2, const float* __restrict__ b2,
    ushort* __restrict__ xa, ushort* __restrict__ xm)
{
    __shared__ float sb[8];
    int row = blockIdx.x; int t = threadIdx.x;
    float v[3]; float s = 0.f, ss = 0.f;
    #pragma unroll
    for (int e=0; e<3; ++e) { v[e] = x[(size_t)row*768 + t + e*256]; s += v[e]; ss += v[e]*v[e]; }
    for (int o=32; o>0; o>>=1){ s += __shfl_down(s,o,64); ss += __shfl_down(ss,o,64); }
    int lane = t&63, w = t>>6;
    if (lane==0){ sb[w]=s; sb[4+w]=ss; }
    __syncthreads();
    s = sb[0]+sb[1]+sb[2]+sb[3]; ss = sb[4]+sb[5]+sb[6]+sb[7];
    float mean = s*(1.f/768.f);
    float var  = ss*(1.f/768.f) - mean*mean;
    float rstd = rsqrtf(var + 1e-5f);
    #pragma unroll
    for (int e=0; e<3; ++e){
        int c = t + e*256;
        float n = (v[e]-mean)*rstd;
        xa[(size_t)row*768 + c] = f2b(n*g1[c] + b1[c]);
        xm[(size_t)row*768 + c] = f2b(n*g2[c] + b2[c]);
    }
}

// ---------------- prep: rope weight tables, reattn-LN wvec, init attn_c(bias) and vsum(0) ----------------
__global__ __launch_bounds__(256) void prep_kernel(
    float* __restrict__ w1t, float* __restrict__ w2t, float* __restrict__ wvec,
    float* __restrict__ attn_c, float* __restrict__ vsum,
    const float* __restrict__ R, const float* __restrict__ rng,
    const float* __restrict__ rnb, const float* __restrict__ bproj)
{
    int idx = blockIdx.x*256 + threadIdx.x;
    {   // rope tables for v-rope (scale = 1/sc)
        int i = idx >> 6, j = idx & 63;
        float w1, w2;
        if (j < 32) {
            int m = j >> 1;
            float inv = powf(10000.f, -(float)m*(1.f/16.f));
            float fr = (float)i * inv;
            float c = cosf(fr), sn = sinf(fr);
            float power = ((float)i - 512.f) * (1.f/512.f);
            float basev = (2.f*(float)(j & 15) + 12.8f) * (1.f/44.8f);
            float sfac = powf(basev, -power);          // 1/sc
            w1 = c * sfac;
            w2 = ((j & 1) ? sn : -sn) * sfac;
        } else { w1 = 1.f; w2 = 0.f; }
        w1t[idx] = w1; w2t[idx] = w2;
    }
    if (blockIdx.x >= 1 && blockIdx.x <= 12) {
        int k = (blockIdx.x-1)*256 + threadIdx.x;  // 0..3071
        int o = k % 768;
        attn_c[k] = bproj[o] + bproj[768 + o];
    }
    if (blockIdx.x >= 13 && blockIdx.x <= 36) {
        int k = (blockIdx.x-13)*256 + threadIdx.x; // 0..6143
        vsum[k] = 0.f;
    }
    if (blockIdx.x == 0) {
        __shared__ float mixs[24];
        __shared__ float ws[24];
        int t = threadIdx.x;
        if (t < 24) {
            int p = t / 12, g = t % 12;
            float m = 0.f;
            for (int h=0; h<12; ++h) m += R[p*144 + h*12 + g];
            mixs[t] = m;
        }
        __syncthreads();
        if (t < 2) {
            float mean=0.f, var=0.f;
            for (int g=0; g<12; ++g) mean += mixs[t*12+g];
            mean *= (1.f/12.f);
            for (int g=0; g<12; ++g){ float d = mixs[t*12+g]-mean; var += d*d; }
            var *= (1.f/12.f);
            float rstd = rsqrtf(var + 1e-5f);
            for (int g=0; g<12; ++g)
                ws[t*12+g] = (mixs[t*12+g]-mean)*rstd*rng[t*12+g] + rnb[t*12+g];
        }
        __syncthreads();
        if (t < 24) wvec[t] = ws[t];
    }
}

// ---------------- vsum[b][pc] += sum_i w1*V + w2*V_neighbor ----------------
__global__ __launch_bounds__(256) void rope_reduce(const ushort* __restrict__ V,
    const float* __restrict__ w1t, const float* __restrict__ w2t, float* __restrict__ vsum)
{
    int col = blockIdx.x*256 + threadIdx.x;
    int b = blockIdx.y;
    int i0 = blockIdx.z * 256;
    int j = col & 63;
    float acc = 0.f;
    const ushort* vp = V + (size_t)(b*1024 + i0)*1536;
    #pragma unroll 4
    for (int i=0; i<256; ++i) {
        float v1 = b2f(vp[(size_t)i*1536 + col]);
        float v2 = b2f(vp[(size_t)i*1536 + (col^1)]);
        int ii = i0 + i;
        acc += w1t[ii*64 + j]*v1 + w2t[ii*64 + j]*v2;
    }
    atomicAdd(&vsum[b*1536 + col], acc);
}

// ---------------- attn_c[b][o] += sum_c (wvec*vsum)[b][c] * Wproj[p][c][o] ----------------
__global__ __launch_bounds__(256) void attn_gemm(const float* __restrict__ vsum,
    const float* __restrict__ wvec, const float* __restrict__ Wproj, float* __restrict__ attn_c)
{
    int o  = blockIdx.x*256 + threadIdx.x;
    int c0 = blockIdx.y * 96;
    int b  = blockIdx.z;
    int p  = c0 / 768;
    float acc = 0.f;
    #pragma unroll 4
    for (int cc=0; cc<96; ++cc) {
        int c = c0 + cc;
        int cl = c - p*768;
        float y = wvec[p*12 + (cl>>6)] * vsum[b*1536 + c];
        acc += y * Wproj[(size_t)p*589824 + (size_t)cl*768 + o];
    }
    atomicAdd(&attn_c[b*768 + o], acc);
}

// ---------------- xf left half: bf16(x + ls1 * attn_c[b]) ----------------
__global__ __launch_bounds__(256) void xf_left(const float* __restrict__ x, const float* __restrict__ ls1,
    const float* __restrict__ attn_c, ushort* __restrict__ xf)
{
    int col = blockIdx.x*256 + threadIdx.x;
    int row = blockIdx.y;
    xf[(size_t)row*1536 + col] = f2b(x[(size_t)row*768 + col] + ls1[col]*attn_c[(row>>10)*768 + col]);
}

// ---------------- gate LN over 1536 ----------------
__global__ __launch_bounds__(256) void ln_gate(const ushort* __restrict__ xg,
    const float* __restrict__ g, const float* __restrict__ bta, ushort* __restrict__ out)
{
    __shared__ float sb[8];
    int row = blockIdx.x, t = threadIdx.x;
    float v[6]; float s=0.f, ss=0.f;
    #pragma unroll
    for (int e=0;e<6;++e){ v[e] = b2f(xg[(size_t)row*1536 + t + e*256]); s+=v[e]; ss+=v[e]*v[e]; }
    for (int o=32; o>0; o>>=1){ s += __shfl_down(s,o,64); ss += __shfl_down(ss,o,64); }
    int lane = t&63, w = t>>6;
    if (lane==0){ sb[w]=s; sb[4+w]=ss; }
    __syncthreads();
    s = sb[0]+sb[1]+sb[2]+sb[3]; ss = sb[4]+sb[5]+sb[6]+sb[7];
    float mean = s*(1.f/1536.f);
    float var  = ss*(1.f/1536.f) - mean*mean;
    float rstd = rsqrtf(var + 1e-5f);
    #pragma unroll
    for (int e=0;e<6;++e){
        int c = t + e*256;
        out[(size_t)row*1536 + c] = f2b((v[e]-mean)*rstd*g[c] + bta[c]);
    }
}

// ---------------- depthwise conv (K=21, same-pad) + xr multiply, LDS sliding window ----------------
// block: 64 channels x 128 output rows; thread: 1 channel x 32 rows
#define CROWS 128
#define CIN   (CROWS + 20)   // 148 staged input rows
#define CSTR  72             // padded LDS row stride (ushorts)
__global__ __launch_bounds__(256) void conv_mul(const ushort* __restrict__ xgln,
    const float* __restrict__ cw, const float* __restrict__ cb,
    const ushort* __restrict__ xr, ushort* __restrict__ u)
{
    __shared__ ushort tile[CIN * CSTR];   // 21312 B
    const int c0 = blockIdx.x * 64;
    const int i0 = blockIdx.y * CROWS;
    const int b  = blockIdx.z;
    const int t  = threadIdx.x;
    const size_t base = (size_t)b*1024*1536;

    // stage rows i0-10 .. i0+137 (zero outside [0,1024))
    #pragma unroll
    for (int it = 0; it < 5; ++it) {
        int idx = it*256 + t;            // uint4 slots: CIN*8 = 1184
        if (idx < CIN*8) {
            int r  = idx >> 3;
            int cq = (idx & 7) * 8;
            int si = i0 + r - 10;
            uint4 val = make_uint4(0u,0u,0u,0u);
            if (si >= 0 && si < 1024)
                val = *(const uint4*)(xgln + base + (size_t)si*1536 + c0 + cq);
            *(uint4*)&tile[r*CSTR + cq] = val;
        }
    }
    __syncthreads();

    const int ch = t & 63;
    const int o0 = (t >> 6) * 32;        // 4 waves x 32 rows = 128
    const int c  = c0 + ch;

    float w[21];
    #pragma unroll
    for (int k=0; k<21; ++k) w[k] = cw[c*21 + k];
    const float bias = cb[c];

    float win[21];
    #pragma unroll
    for (int j=0; j<20; ++j) win[j] = b2f(tile[(o0+j)*CSTR + ch]);

    #pragma unroll
    for (int j=0; j<32; ++j) {
        win[(j+20)%21] = b2f(tile[(o0+j+20)*CSTR + ch]);
        float acc = bias;
        #pragma unroll
        for (int k=0; k<21; ++k) acc += win[(j+k)%21] * w[k];
        size_t off = base + (size_t)(i0+o0+j)*1536 + c;
        u[off] = f2b(b2f(xr[off]) * acc);
    }
}

extern "C" void kernel_launch(void* const* d_in, const int* in_sizes, int n_in,
                              void* d_out, int out_size, void* d_ws, size_t ws_size,
                              hipStream_t stream)
{
    const float* x     = (const float*)d_in[0];
    const float* Wqkv  = (const float*)d_in[1];
    const float* bqkv  = (const float*)d_in[2];
    const float* Wproj = (const float*)d_in[3];
    const float* bproj = (const float*)d_in[4];
    const float* Rw    = (const float*)d_in[9];
    const float* rng   = (const float*)d_in[10];
    const float* rnb   = (const float*)d_in[11];
    const float* ln1g  = (const float*)d_in[12];
    const float* ln1b  = (const float*)d_in[13];
    const float* ln2g  = (const float*)d_in[14];
    const float* ln2b  = (const float*)d_in[15];
    const float* ls1   = (const float*)d_in[16];
    const float* ls2   = (const float*)d_in[17];
    const float* W1    = (const float*)d_in[18];
    const float* b1    = (const float*)d_in[19];
    const float* gng   = (const float*)d_in[20];
    const float* gnb   = (const float*)d_in[21];
    const float* cw    = (const float*)d_in[22];
    const float* cb    = (const float*)d_in[23];
    const float* W2    = (const float*)d_in[24];
    const float* b2    = (const float*)d_in[25];
    const float* Wout  = (const float*)d_in[26];
    const float* bout  = (const float*)d_in[27];
    float* out = (float*)d_out;

    char* ws = (char*)d_ws;
    size_t off = 0;
    auto alloc = [&](size_t bytes)->char* {
        char* p = ws + off;
        off += (bytes + 255) & ~(size_t)255;
        return p;
    };
    ushort* WvT   = (ushort*)alloc(1536*768*2);   // [pc][k]
    ushort* W1T   = (ushort*)alloc(3072*768*2);
    ushort* W2T   = (ushort*)alloc(768*1536*2);
    ushort* WoutT = (ushort*)alloc(768*1536*2);
    float*  bvp   = (float*)alloc(1536*4);
    float*  w1t   = (float*)alloc(65536*4);
    float*  w2t   = (float*)alloc(65536*4);
    float*  wvec  = (float*)alloc(24*4);
    float*  attnc = (float*)alloc(3072*4);
    float*  vsum  = (float*)alloc(6144*4);
    ushort* xa16  = (ushort*)alloc(4096*768*2);
    ushort* xm16  = (ushort*)alloc(4096*768*2);   // xa16+xm16 contiguous -> xgln alias
    ushort* V16   = (ushort*)alloc(4096*1536*2);  // aliased by xr16 after rope_reduce
    ushort* xg16  = (ushort*)alloc(4096*1536*2);  // aliased by u16 after ln_gate
    ushort* xf16  = (ushort*)alloc(4096*1536*2);
    ushort* xgln  = xa16;   // reuses xa16+xm16 region (dead by then)
    ushort* xr16  = V16;
    ushort* u16   = xg16;
    (void)ws_size; (void)n_in; (void)in_sizes; (void)out_size;

    // ---- weight packs ----
    for (int p = 0; p < 2; ++p)
        pack_bt<<<dim3(24, 24), 256, 0, stream>>>(Wqkv + (size_t)p*768*2304, WvT + (size_t)p*768*768,
                                                  768, 2304, 1536);
    pack_bt<<<dim3(24, 96), 256, 0, stream>>>(W1,   W1T,   768,  3072, 0);
    pack_bt<<<dim3(48, 24), 256, 0, stream>>>(W2,   W2T,   1536, 768,  0);
    pack_bt<<<dim3(48, 24), 256, 0, stream>>>(Wout, WoutT, 1536, 768,  0);
    pack_bv<<<dim3(6), 256, 0, stream>>>(bqkv, bvp);
    prep_kernel<<<dim3(256), 256, 0, stream>>>(w1t, w2t, wvec, attnc, vsum, Rw, rng, rnb, bproj);

    // ---- shared LN ----
    ln_x_kernel<<<dim3(4096), 256, 0, stream>>>(x, ln1g, ln1b, ln2g, ln2b, xa16, xm16);

    // ---- V projection (both paths) ----
    gemm_bf16<0><<<dim3(12, 32), 256, 0, stream>>>(xa16, WvT, 4096, 1536, 768,
                                                   bvp, nullptr, nullptr, V16, nullptr, nullptr);
    // ---- rope-weighted sequence sum ----
    rope_reduce<<<dim3(6, 4, 4), 256, 0, stream>>>(V16, w1t, w2t, vsum);
    // ---- reattn projection to per-batch constant ----
    attn_gemm<<<dim3(3, 16, 4), 256, 0, stream>>>(vsum, wvec, Wproj, attnc);
    // ---- xf left half ----
    xf_left<<<dim3(3, 4096), 256, 0, stream>>>(x, ls1, attnc, xf16);

    // ---- MLP ----
    gemm_bf16<1><<<dim3(24, 32), 256, 0, stream>>>(xm16, W1T, 4096, 3072, 768,
                                                   b1, nullptr, nullptr, xr16, xg16, nullptr);
    ln_gate<<<dim3(4096), 256, 0, stream>>>(xg16, gng, gnb, xgln);
    conv_mul<<<dim3(24, 8, 4), 256, 0, stream>>>(xgln, cw, cb, xr16, u16);
    gemm_bf16<2><<<dim3(6, 32), 256, 0, stream>>>(u16, W2T, 4096, 768, 1536,
                                                  b2, ls2, x, xf16, nullptr, nullptr);
    // ---- final projection + residual ----
    gemm_bf16<3><<<dim3(6, 32), 256, 0, stream>>>(xf16, WoutT, 4096, 768, 1536,
                                                  bout, nullptr, x, nullptr, nullptr, out);
}